// Round 1
// baseline (371.621 us; speedup 1.0000x reference)
//
#include <hip/hip_runtime.h>
#include <stdint.h>

typedef unsigned short u16;
typedef unsigned int u32;
typedef __attribute__((ext_vector_type(8))) short bf16x8;
typedef __attribute__((ext_vector_type(4))) float f32x4;

#define S_LEN 4032
#define S_PAD 4096
#define DIMC  1536
#define HD    128
#define FRAME 448

static const size_t OFF_FLAG  = 0;
static const size_t OFF_CANON = 256;
static const size_t OFF_XB    = 524288;
static const size_t OFF_WT    = OFF_XB  + 12582912;
static const size_t OFF_WOT   = OFF_WT  + 14155776;
static const size_t OFF_YQ    = OFF_WOT + 4718592;
static const size_t OFF_YK    = OFF_YQ  + 12582912;
static const size_t OFF_VT    = OFF_YK  + 12582912;
static const size_t OFF_QH    = OFF_VT  + 12582912;
static const size_t OFF_KH    = OFF_QH  + 12386304;
static const size_t OFF_AT    = OFF_KH  + 12386304;
static const size_t WS_NEED   = OFF_AT  + 12582912;

#define C_BQ 0
#define C_BO 4608
#define C_GQ 6144
#define C_GK 7680
#define C_FR 9216
#define C_TOT 74752

__device__ __forceinline__ u16 f2bf(float f) {
  union { float f; u32 u; } v; v.f = f;
  u32 u = v.u;
  u32 r = (u + 0x7fffu + ((u >> 16) & 1u)) >> 16;
  return (u16)r;
}
__device__ __forceinline__ float bf2f(u16 h) {
  union { float f; u32 u; } v; v.u = ((u32)h) << 16;
  return v.f;
}

__device__ __forceinline__ void gld_lds16(const void* g, void* l) {
  __builtin_amdgcn_global_load_lds(
      (const __attribute__((address_space(1))) void*)(uintptr_t)g,
      (__attribute__((address_space(3))) void*)(u32)(uintptr_t)l,
      16, 0, 0);
}

__device__ __forceinline__ f32x4 mfma16(bf16x8 a, bf16x8 b, f32x4 c) {
  return __builtin_amdgcn_mfma_f32_16x16x32_bf16(a, b, c, 0, 0, 0);
}

// ---------------- fused preprocessing: detect + transpose_w + convert_x + small ----------------
__global__ void prep_all(const void* __restrict__ x,
                         const void* Wq, const void* Wk, const void* Wv, const void* Wo,
                         const void* bq, const void* bk, const void* bv, const void* bo,
                         const void* gq, const void* gk, const void* fr,
                         float* __restrict__ canon, u16* __restrict__ xb,
                         u16* __restrict__ wqkvt, u16* __restrict__ wot,
                         int* __restrict__ flag) {
  __shared__ int cnt;
  __shared__ float tile[32][33];
  const int tid = threadIdx.x;
  if (tid == 0) cnt = 0;
  __syncthreads();
  int e = (((const u16*)x)[2 * tid] >> 7) & 0xff;
  if (e > 150) atomicAdd(&cnt, 1);
  __syncthreads();
  const int fl = (cnt >= 8) ? 1 : 0;   // 1 = fp32 inputs, 0 = bf16
  const int bid = blockIdx.x;
  if (bid == 0 && tid == 0) *flag = fl;

  if (bid < 9216) {
    // ---- W (K x N) -> Wt (N x K) bf16 ----
    const int z = bid / 2304;
    const int rem = bid % 2304;
    const int by = rem / 48, bx = rem % 48;
    const void* W = (z == 0) ? Wq : (z == 1) ? Wk : (z == 2) ? Wv : Wo;
    u16* dst = (z < 3) ? (wqkvt + (size_t)z * DIMC * DIMC) : wot;
    const int tx = tid & 31, ty = tid >> 5;
    const int c = bx * 32 + tx;
    #pragma unroll
    for (int i = 0; i < 4; i++) {
      int r = by * 32 + ty + i * 8;
      float v = fl ? ((const float*)W)[(size_t)r * DIMC + c]
                   : bf2f(((const u16*)W)[(size_t)r * DIMC + c]);
      tile[ty + i * 8][tx] = v;
    }
    __syncthreads();
    const int k = by * 32 + tx;
    #pragma unroll
    for (int i = 0; i < 4; i++) {
      int n = bx * 32 + ty + i * 8;
      dst[(size_t)n * DIMC + k] = f2bf(tile[tx][ty + i * 8]);
    }
  } else if (bid < 12288) {
    // ---- x -> bf16, pad rows to 4096 ----
    int i = (bid - 9216) * 256 + tid;
    if (i < (S_PAD * DIMC) / 8) {
      size_t base = (size_t)i * 8;
      int row = (int)(base / DIMC);
      union { u16 h[8]; uint4 v; } u;
      if (row < S_LEN) {
        if (fl) {
          const float* xf = (const float*)x + base;
          #pragma unroll
          for (int j = 0; j < 8; j++) u.h[j] = f2bf(xf[j]);
        } else {
          const u16* xh = (const u16*)x + base;
          #pragma unroll
          for (int j = 0; j < 8; j++) u.h[j] = xh[j];
        }
      } else {
        #pragma unroll
        for (int j = 0; j < 8; j++) u.h[j] = 0;
      }
      ((uint4*)xb)[i] = u.v;
    }
  } else {
    // ---- small tensors -> canonical fp32 ----
    for (int i = (bid - 12288) * 256 + tid; i < C_TOT; i += 292 * 256) {
      const void* src; int j;
      if      (i < 1536) { src = bq; j = i; }
      else if (i < 3072) { src = bk; j = i - 1536; }
      else if (i < 4608) { src = bv; j = i - 3072; }
      else if (i < 6144) { src = bo; j = i - 4608; }
      else if (i < 7680) { src = gq; j = i - 6144; }
      else if (i < 9216) { src = gk; j = i - 7680; }
      else               { src = fr; j = i - 9216; }
      canon[i] = fl ? ((const float*)src)[j] : bf2f(((const u16*)src)[j]);
    }
  }
}

// ---------------- GEMM: C(MxN) = A(MxK) @ Bt(NxK)^T + bias ----------------
template <int MODE>
__launch_bounds__(256, 4)
__global__ void gemm_bt(const u16* __restrict__ A, const u16* __restrict__ Bt,
                        const float* __restrict__ canon,
                        u16* __restrict__ Yq, u16* __restrict__ Yk, u16* __restrict__ Vt,
                        void* __restrict__ Out, const int* __restrict__ flagp) {
  const int bm0 = blockIdx.y * 128, bn0 = blockIdx.x * 128;
  const int tid = threadIdx.x, wave = tid >> 6, lane = tid & 63;
  const int wm = wave >> 1, wn = wave & 1;
  const int l15 = lane & 15, l4 = lane >> 4;
  __shared__ u16 sA[128 * 64];
  __shared__ u16 sB[128 * 64];
  f32x4 acc[4][4];
  #pragma unroll
  for (int i = 0; i < 4; i++)
    #pragma unroll
    for (int j = 0; j < 4; j++) acc[i][j] = (f32x4){0.f, 0.f, 0.f, 0.f};

  const int swc = ((lane & 7) ^ (lane >> 3)) * 8;
  const u16* Ab = A  + (size_t)(bm0 + (lane >> 3)) * DIMC + swc;
  const u16* Bb = Bt + (size_t)(bn0 + (lane >> 3)) * DIMC + swc;

  for (int kt = 0; kt < DIMC; kt += 64) {
    __syncthreads();
    #pragma unroll
    for (int c = 0; c < 4; c++) {
      int g = wave * 4 + c;
      gld_lds16(Ab + (size_t)g * 8 * DIMC + kt, (char*)sA + g * 1024);
      gld_lds16(Bb + (size_t)g * 8 * DIMC + kt, (char*)sB + g * 1024);
    }
    __syncthreads();
    #pragma unroll
    for (int ks = 0; ks < 2; ks++) {
      bf16x8 av[4], bvv[4];
      #pragma unroll
      for (int mt = 0; mt < 4; mt++)
        av[mt]  = *(const bf16x8*)(sA + (wm * 64 + mt * 16 + l15) * 64 +
                                   (((ks * 4 + l4) ^ (l15 & 7)) * 8));
      #pragma unroll
      for (int nt = 0; nt < 4; nt++)
        bvv[nt] = *(const bf16x8*)(sB + (wn * 64 + nt * 16 + l15) * 64 +
                                   (((ks * 4 + l4) ^ (l15 & 7)) * 8));
      #pragma unroll
      for (int mt = 0; mt < 4; mt++)
        #pragma unroll
        for (int nt = 0; nt < 4; nt++)
          acc[mt][nt] = mfma16(av[mt], bvv[nt], acc[mt][nt]);
    }
  }

  const int gm0 = bm0 + wm * 64;
  const int gn0 = bn0 + wn * 64;
  if (MODE == 0) {
    #pragma unroll
    for (int nt = 0; nt < 4; nt++) {
      int gn = gn0 + nt * 16 + l15;
      float b = canon[C_BQ + gn];
      #pragma unroll
      for (int mt = 0; mt < 4; mt++) {
        int gm = gm0 + mt * 16 + l4 * 4;
        if (gn < 1536) {
          #pragma unroll
          for (int r = 0; r < 4; r++)
            Yq[(size_t)(gm + r) * DIMC + gn] = f2bf(acc[mt][nt][r] + b);
        } else if (gn < 3072) {
          int g2 = gn - 1536;
          #pragma unroll
          for (int r = 0; r < 4; r++)
            Yk[(size_t)(gm + r) * DIMC + g2] = f2bf(acc[mt][nt][r] + b);
        } else {
          int g2 = gn - 3072;
          u32 lo = (u32)f2bf(acc[mt][nt][0] + b) | ((u32)f2bf(acc[mt][nt][1] + b) << 16);
          u32 hi = (u32)f2bf(acc[mt][nt][2] + b) | ((u32)f2bf(acc[mt][nt][3] + b) << 16);
          uint2 pk; pk.x = lo; pk.y = hi;
          *(uint2*)(Vt + (size_t)g2 * S_PAD + gm) = pk;
        }
      }
    }
  } else {
    const int fl = *flagp;
    #pragma unroll
    for (int nt = 0; nt < 4; nt++) {
      int gn = gn0 + nt * 16 + l15;
      float b = canon[C_BO + gn];
      #pragma unroll
      for (int mt = 0; mt < 4; mt++) {
        int gm = gm0 + mt * 16 + l4 * 4;
        #pragma unroll
        for (int r = 0; r < 4; r++) {
          int gr = gm + r;
          if (gr < S_LEN) {
            float v = acc[mt][nt][r] + b;
            if (fl) ((float*)Out)[(size_t)gr * DIMC + gn] = v;
            else    ((u16*)Out)[(size_t)gr * DIMC + gn] = f2bf(v);
          }
        }
      }
    }
  }
}

// ---------------- fused RMSNorm + RoPE, wave-per-row ----------------
__global__ void norm_rope(const u16* __restrict__ Yq, const u16* __restrict__ Yk,
                          const float* __restrict__ canon, u16* __restrict__ Qh,
                          u16* __restrict__ Kh) {
  const int tid = threadIdx.x, wave = tid >> 6, lane = tid & 63;
  const int s = blockIdx.x * 4 + wave;
  const int isq = (blockIdx.y == 0);
  const u16* Y = isq ? Yq : Yk;
  const float* g = canon + (isq ? C_GQ : C_GK);
  u16* Oh = isq ? Qh : Kh;
  const float sc = isq ? (0.08838834764831845f * 1.4426950408889634f) : 1.0f;

  const u32* yrow = (const u32*)Y + (size_t)s * 768;
  float xr[12], xi[12];
  float ss = 0.f;
  #pragma unroll
  for (int i = 0; i < 12; i++) {
    u32 d = yrow[lane + 64 * i];
    float a = bf2f((u16)(d & 0xffff));
    float b = bf2f((u16)(d >> 16));
    xr[i] = a; xi[i] = b;
    ss += a * a + b * b;
  }
  #pragma unroll
  for (int dd = 1; dd < 64; dd <<= 1) ss += __shfl_xor(ss, dd, 64);
  float rms = rsqrtf(ss * (1.f / 1536.f) + 1e-6f);

  int f_ = s / FRAME, hh = (s % FRAME) / 28, ww = s % 28;
  const float* fr = canon + C_FR;
  float a = (lane < 22) ? fr[f_ * 64 + lane]
          : (lane < 43) ? fr[hh * 64 + lane]
                        : fr[ww * 64 + lane];
  float si, co;
  __sincosf(a, &si, &co);

  const float2* g2 = (const float2*)g;
  #pragma unroll
  for (int i = 0; i < 12; i++) {
    int p = lane + 64 * i;
    float2 gg = g2[p];
    float r  = xr[i] * rms * gg.x;
    float im = xi[i] * rms * gg.y;
    u32 pk = (u32)f2bf((r * co - im * si) * sc) | ((u32)f2bf((r * si + im * co) * sc) << 16);
    ((u32*)Oh)[((size_t)i * S_LEN + s) * 64 + lane] = pk;
  }
}

// ---------------- flash attention v6: 112-row Q tile, 7 waves x 16 q-rows ----------------
// Restructure of v5: no split-KV (no cross-wave merge), one shared K/V tile per
// iteration, LDS 80KB -> 46KB so 2 blocks/CU co-resident = 14 waves/CU (was 8),
// and 112-q tiles cut K/V staging traffic by 0.57x. All swizzle/layout formulas
// carried over verbatim from the verified v5.
__launch_bounds__(448, 4)
__global__ void attn_v6(const u16* __restrict__ Qh, const u16* __restrict__ Kh,
                        const u16* __restrict__ Vt, u16* __restrict__ Ab) {
  const int tid = threadIdx.x, wave = tid >> 6, lane = tid & 63;
  const int l15 = lane & 15, l4 = lane >> 4;
  const int h = blockIdx.x % 12;
  const int qb = 35 - (blockIdx.x / 12);      // heavy blocks first
  const int q0 = qb * 112;                    // 112*4 == FRAME: whole tile in one frame
  const int nkv = (q0 / FRAME + 1) * 7;       // full 64-wide KV tiles, no masking needed
  __shared__ u16 sK[8192];       // 64 kv x 128 d (xor-swizzled rows)
  __shared__ u16 sV[8192];       // 128 d x 64 kv (xor-swizzled rows)
  __shared__ u16 sP[7][1024];    // per-wave P tile: 64 kv x 16 q

  // staging offsets: 1024 16B-chunks per tile over 448 threads (i=2 only tid<128,
  // which is waves 0/1 entirely -> no partial-wave gld_lds)
  int koff[3], voff[3];
  #pragma unroll
  for (int i = 0; i < 3; i++) {
    int c = i * 448 + tid;
    int r = c >> 4, cc = (c & 15) ^ (r & 15);
    koff[i] = r * HD + cc * 8;
    int rv = c >> 3, cv = (c & 7) ^ (rv & 7);
    voff[i] = rv * S_PAD + cv * 8;
  }

  // Q fragments: wave owns rows q0 + wave*16 .. +15
  bf16x8 qf[4];
  {
    const u16* qp = Qh + ((size_t)h * S_LEN + q0 + wave * 16 + l15) * HD + l4 * 8;
    #pragma unroll
    for (int ks = 0; ks < 4; ks++) qf[ks] = *(const bf16x8*)(qp + ks * 32);
  }
  f32x4 o[8];
  #pragma unroll
  for (int i = 0; i < 8; i++) o[i] = (f32x4){0.f, 0.f, 0.f, 0.f};
  float l_i = 0.f;

  const u16* kb0 = Kh + (size_t)h * S_LEN * HD;
  const u16* vb0 = Vt + (size_t)h * HD * S_PAD;

  for (int t = 0; t < nkv; ++t) {
    __syncthreads();                         // previous tile fully consumed
    const u16* kb = kb0 + (size_t)t * 64 * HD;
    const u16* vb = vb0 + t * 64;
    #pragma unroll
    for (int i = 0; i < 3; i++) {
      int c = i * 448 + tid;
      if (c < 1024) {
        gld_lds16(kb + koff[i], (char*)sK + (size_t)(c - lane) * 16);
        gld_lds16(vb + voff[i], (char*)sV + (size_t)(c - lane) * 16);
      }
    }
    __syncthreads();                         // staging complete (vmcnt drained)

    // ---- QK^T: sT[nt][r] = S[kv = nt*16 + l4*4 + r][q = l15] ----
    f32x4 sT[4];
    #pragma unroll
    for (int nt = 0; nt < 4; nt++) sT[nt] = (f32x4){0.f, 0.f, 0.f, 0.f};
    __builtin_amdgcn_s_setprio(1);
    #pragma unroll
    for (int ks = 0; ks < 4; ks++) {
      bf16x8 kf[4];
      #pragma unroll
      for (int nt = 0; nt < 4; nt++)
        kf[nt] = *(const bf16x8*)(sK + (nt * 16 + l15) * HD + (((ks * 4 + l4) ^ l15) * 8));
      #pragma unroll
      for (int nt = 0; nt < 4; nt++)
        sT[nt] = mfma16(kf[nt], qf[ks], sT[nt]);
    }
    __builtin_amdgcn_s_setprio(0);

    // ---- softmax numerator (q pre-scaled by log2e*scale), pack to sP ----
    float rs = 0.f;
    u16* pw = sP[wave];
    #pragma unroll
    for (int nt = 0; nt < 4; nt++) {
      #pragma unroll
      for (int r = 0; r < 4; r++) {
        float p = __builtin_amdgcn_exp2f(sT[nt][r]);
        sT[nt][r] = p; rs += p;
      }
      u32 lo = (u32)f2bf(sT[nt][0]) | ((u32)f2bf(sT[nt][1]) << 16);
      u32 hi = (u32)f2bf(sT[nt][2]) | ((u32)f2bf(sT[nt][3]) << 16);
      u32 off = (u32)((nt >> 1) * 512 + ((nt & 1) * 2 + (l4 >> 1)) * 128 + l15 * 8 + (l4 & 1) * 4);
      uint2 pk; pk.x = lo; pk.y = hi;
      *(uint2*)(pw + off) = pk;
    }
    l_i += rs;

    // ---- PV: o[vt] += V^T frag x P frag ----
    #pragma unroll
    for (int ks2 = 0; ks2 < 2; ks2++) {
      bf16x8 pb = *(const bf16x8*)(sP[wave] + ks2 * 512 + lane * 8);
      __builtin_amdgcn_s_setprio(1);
      #pragma unroll
      for (int vt = 0; vt < 8; vt++) {
        bf16x8 vf = *(const bf16x8*)(sV + (vt * 16 + l15) * 64 + (((ks2 * 4 + l4) ^ (l15 & 7)) * 8));
        o[vt] = mfma16(vf, pb, o[vt]);
      }
      __builtin_amdgcn_s_setprio(0);
    }
  }

  // ---- epilogue: per-wave, no cross-wave merge ----
  l_i += __shfl_xor(l_i, 16, 64);
  l_i += __shfl_xor(l_i, 32, 64);
  float inv = 1.f / l_i;
  const size_t orow = (size_t)(q0 + wave * 16 + l15) * DIMC + (size_t)h * HD;
  #pragma unroll
  for (int vt = 0; vt < 8; vt++) {
    u32 lo = (u32)f2bf(o[vt][0] * inv) | ((u32)f2bf(o[vt][1] * inv) << 16);
    u32 hi = (u32)f2bf(o[vt][2] * inv) | ((u32)f2bf(o[vt][3] * inv) << 16);
    uint2 pk; pk.x = lo; pk.y = hi;
    *(uint2*)(Ab + orow + vt * 16 + l4 * 4) = pk;
  }
}

extern "C" void kernel_launch(void* const* d_in, const int* in_sizes, int n_in,
                              void* d_out, int out_size, void* d_ws, size_t ws_size,
                              hipStream_t stream) {
  if (ws_size < WS_NEED) return;
  char* ws = (char*)d_ws;
  int*   flag  = (int*)(ws + OFF_FLAG);
  float* canon = (float*)(ws + OFF_CANON);
  u16* xb    = (u16*)(ws + OFF_XB);
  u16* wqkvt = (u16*)(ws + OFF_WT);
  u16* wot   = (u16*)(ws + OFF_WOT);
  u16* yq    = (u16*)(ws + OFF_YQ);
  u16* yk    = (u16*)(ws + OFF_YK);
  u16* vt    = (u16*)(ws + OFF_VT);
  u16* qh    = (u16*)(ws + OFF_QH);
  u16* kh    = (u16*)(ws + OFF_KH);
  u16* ab    = (u16*)(ws + OFF_AT);

  const void* x  = d_in[0];
  const void* fr = d_in[3];
  const void* Wq = d_in[4];  const void* bq = d_in[5];
  const void* Wk = d_in[6];  const void* bk = d_in[7];
  const void* Wv = d_in[8];  const void* bv = d_in[9];
  const void* Wo = d_in[10]; const void* bo = d_in[11];
  const void* gq = d_in[12]; const void* gk = d_in[13];

  prep_all<<<12580, 256, 0, stream>>>(x, Wq, Wk, Wv, Wo, bq, bk, bv, bo, gq, gk, fr,
                                      canon, xb, wqkvt, wot, flag);
  gemm_bt<0><<<dim3(36, 32), 256, 0, stream>>>(xb, wqkvt, canon, yq, yk, vt, nullptr, flag);
  norm_rope<<<dim3(1008, 2), 256, 0, stream>>>(yq, yk, canon, qh, kh);
  attn_v6<<<432, 448, 0, stream>>>(qh, kh, vt, ab);
  gemm_bt<1><<<dim3(12, 32), 256, 0, stream>>>(ab, wot, canon, nullptr, nullptr, nullptr, d_out, flag);
}

// Round 2
// 339.731 us; speedup vs baseline: 1.0939x; 1.0939x over previous
//
#include <hip/hip_runtime.h>
#include <stdint.h>

typedef unsigned short u16;
typedef unsigned int u32;
typedef __attribute__((ext_vector_type(8))) short bf16x8;
typedef __attribute__((ext_vector_type(4))) float f32x4;

#define S_LEN 4032
#define S_PAD 4096
#define DIMC  1536
#define HD    128
#define FRAME 448

static const size_t OFF_FLAG  = 0;
static const size_t OFF_CANON = 256;
static const size_t OFF_XB    = 524288;
static const size_t OFF_WT    = OFF_XB  + 12582912;
static const size_t OFF_WOT   = OFF_WT  + 14155776;
static const size_t OFF_YQ    = OFF_WOT + 4718592;
static const size_t OFF_YK    = OFF_YQ  + 12582912;
static const size_t OFF_VT    = OFF_YK  + 12582912;
static const size_t OFF_QH    = OFF_VT  + 12582912;
static const size_t OFF_KH    = OFF_QH  + 12386304;
static const size_t OFF_AT    = OFF_KH  + 12386304;
static const size_t WS_NEED   = OFF_AT  + 12582912;

#define C_BQ 0
#define C_BO 4608
#define C_GQ 6144
#define C_GK 7680
#define C_FR 9216
#define C_TOT 74752

__device__ __forceinline__ u16 f2bf(float f) {
  union { float f; u32 u; } v; v.f = f;
  u32 u = v.u;
  u32 r = (u + 0x7fffu + ((u >> 16) & 1u)) >> 16;
  return (u16)r;
}
__device__ __forceinline__ float bf2f(u16 h) {
  union { float f; u32 u; } v; v.u = ((u32)h) << 16;
  return v.f;
}

__device__ __forceinline__ void gld_lds16(const void* g, void* l) {
  __builtin_amdgcn_global_load_lds(
      (const __attribute__((address_space(1))) void*)(uintptr_t)g,
      (__attribute__((address_space(3))) void*)(u32)(uintptr_t)l,
      16, 0, 0);
}

__device__ __forceinline__ f32x4 mfma16(bf16x8 a, bf16x8 b, f32x4 c) {
  return __builtin_amdgcn_mfma_f32_16x16x32_bf16(a, b, c, 0, 0, 0);
}

// ---------------- fused preprocessing: detect + transpose_w + convert_x + small ----------------
__global__ void prep_all(const void* __restrict__ x,
                         const void* Wq, const void* Wk, const void* Wv, const void* Wo,
                         const void* bq, const void* bk, const void* bv, const void* bo,
                         const void* gq, const void* gk, const void* fr,
                         float* __restrict__ canon, u16* __restrict__ xb,
                         u16* __restrict__ wqkvt, u16* __restrict__ wot,
                         int* __restrict__ flag) {
  __shared__ int cnt;
  __shared__ float tile[32][33];
  const int tid = threadIdx.x;
  if (tid == 0) cnt = 0;
  __syncthreads();
  int e = (((const u16*)x)[2 * tid] >> 7) & 0xff;
  if (e > 150) atomicAdd(&cnt, 1);
  __syncthreads();
  const int fl = (cnt >= 8) ? 1 : 0;   // 1 = fp32 inputs, 0 = bf16
  const int bid = blockIdx.x;
  if (bid == 0 && tid == 0) *flag = fl;

  if (bid < 9216) {
    // ---- W (K x N) -> Wt (N x K) bf16 ----
    const int z = bid / 2304;
    const int rem = bid % 2304;
    const int by = rem / 48, bx = rem % 48;
    const void* W = (z == 0) ? Wq : (z == 1) ? Wk : (z == 2) ? Wv : Wo;
    u16* dst = (z < 3) ? (wqkvt + (size_t)z * DIMC * DIMC) : wot;
    const int tx = tid & 31, ty = tid >> 5;
    const int c = bx * 32 + tx;
    #pragma unroll
    for (int i = 0; i < 4; i++) {
      int r = by * 32 + ty + i * 8;
      float v = fl ? ((const float*)W)[(size_t)r * DIMC + c]
                   : bf2f(((const u16*)W)[(size_t)r * DIMC + c]);
      tile[ty + i * 8][tx] = v;
    }
    __syncthreads();
    const int k = by * 32 + tx;
    #pragma unroll
    for (int i = 0; i < 4; i++) {
      int n = bx * 32 + ty + i * 8;
      dst[(size_t)n * DIMC + k] = f2bf(tile[tx][ty + i * 8]);
    }
  } else if (bid < 12288) {
    // ---- x -> bf16, pad rows to 4096 ----
    int i = (bid - 9216) * 256 + tid;
    if (i < (S_PAD * DIMC) / 8) {
      size_t base = (size_t)i * 8;
      int row = (int)(base / DIMC);
      union { u16 h[8]; uint4 v; } u;
      if (row < S_LEN) {
        if (fl) {
          const float* xf = (const float*)x + base;
          #pragma unroll
          for (int j = 0; j < 8; j++) u.h[j] = f2bf(xf[j]);
        } else {
          const u16* xh = (const u16*)x + base;
          #pragma unroll
          for (int j = 0; j < 8; j++) u.h[j] = xh[j];
        }
      } else {
        #pragma unroll
        for (int j = 0; j < 8; j++) u.h[j] = 0;
      }
      ((uint4*)xb)[i] = u.v;
    }
  } else {
    // ---- small tensors -> canonical fp32 ----
    for (int i = (bid - 12288) * 256 + tid; i < C_TOT; i += 292 * 256) {
      const void* src; int j;
      if      (i < 1536) { src = bq; j = i; }
      else if (i < 3072) { src = bk; j = i - 1536; }
      else if (i < 4608) { src = bv; j = i - 3072; }
      else if (i < 6144) { src = bo; j = i - 4608; }
      else if (i < 7680) { src = gq; j = i - 6144; }
      else if (i < 9216) { src = gk; j = i - 7680; }
      else               { src = fr; j = i - 9216; }
      canon[i] = fl ? ((const float*)src)[j] : bf2f(((const u16*)src)[j]);
    }
  }
}

// ---------------- GEMM: C(MxN) = A(MxK) @ Bt(NxK)^T + bias ----------------
template <int MODE>
__launch_bounds__(256, 4)
__global__ void gemm_bt(const u16* __restrict__ A, const u16* __restrict__ Bt,
                        const float* __restrict__ canon,
                        u16* __restrict__ Yq, u16* __restrict__ Yk, u16* __restrict__ Vt,
                        void* __restrict__ Out, const int* __restrict__ flagp) {
  const int bm0 = blockIdx.y * 128, bn0 = blockIdx.x * 128;
  const int tid = threadIdx.x, wave = tid >> 6, lane = tid & 63;
  const int wm = wave >> 1, wn = wave & 1;
  const int l15 = lane & 15, l4 = lane >> 4;
  __shared__ u16 sA[128 * 64];
  __shared__ u16 sB[128 * 64];
  f32x4 acc[4][4];
  #pragma unroll
  for (int i = 0; i < 4; i++)
    #pragma unroll
    for (int j = 0; j < 4; j++) acc[i][j] = (f32x4){0.f, 0.f, 0.f, 0.f};

  const int swc = ((lane & 7) ^ (lane >> 3)) * 8;
  const u16* Ab = A  + (size_t)(bm0 + (lane >> 3)) * DIMC + swc;
  const u16* Bb = Bt + (size_t)(bn0 + (lane >> 3)) * DIMC + swc;

  for (int kt = 0; kt < DIMC; kt += 64) {
    __syncthreads();
    #pragma unroll
    for (int c = 0; c < 4; c++) {
      int g = wave * 4 + c;
      gld_lds16(Ab + (size_t)g * 8 * DIMC + kt, (char*)sA + g * 1024);
      gld_lds16(Bb + (size_t)g * 8 * DIMC + kt, (char*)sB + g * 1024);
    }
    __syncthreads();
    #pragma unroll
    for (int ks = 0; ks < 2; ks++) {
      bf16x8 av[4], bvv[4];
      #pragma unroll
      for (int mt = 0; mt < 4; mt++)
        av[mt]  = *(const bf16x8*)(sA + (wm * 64 + mt * 16 + l15) * 64 +
                                   (((ks * 4 + l4) ^ (l15 & 7)) * 8));
      #pragma unroll
      for (int nt = 0; nt < 4; nt++)
        bvv[nt] = *(const bf16x8*)(sB + (wn * 64 + nt * 16 + l15) * 64 +
                                   (((ks * 4 + l4) ^ (l15 & 7)) * 8));
      #pragma unroll
      for (int mt = 0; mt < 4; mt++)
        #pragma unroll
        for (int nt = 0; nt < 4; nt++)
          acc[mt][nt] = mfma16(av[mt], bvv[nt], acc[mt][nt]);
    }
  }

  const int gm0 = bm0 + wm * 64;
  const int gn0 = bn0 + wn * 64;
  if (MODE == 0) {
    #pragma unroll
    for (int nt = 0; nt < 4; nt++) {
      int gn = gn0 + nt * 16 + l15;
      float b = canon[C_BQ + gn];
      #pragma unroll
      for (int mt = 0; mt < 4; mt++) {
        int gm = gm0 + mt * 16 + l4 * 4;
        if (gn < 1536) {
          #pragma unroll
          for (int r = 0; r < 4; r++)
            Yq[(size_t)(gm + r) * DIMC + gn] = f2bf(acc[mt][nt][r] + b);
        } else if (gn < 3072) {
          int g2 = gn - 1536;
          #pragma unroll
          for (int r = 0; r < 4; r++)
            Yk[(size_t)(gm + r) * DIMC + g2] = f2bf(acc[mt][nt][r] + b);
        } else {
          int g2 = gn - 3072;
          u32 lo = (u32)f2bf(acc[mt][nt][0] + b) | ((u32)f2bf(acc[mt][nt][1] + b) << 16);
          u32 hi = (u32)f2bf(acc[mt][nt][2] + b) | ((u32)f2bf(acc[mt][nt][3] + b) << 16);
          uint2 pk; pk.x = lo; pk.y = hi;
          *(uint2*)(Vt + (size_t)g2 * S_PAD + gm) = pk;
        }
      }
    }
  } else {
    const int fl = *flagp;
    #pragma unroll
    for (int nt = 0; nt < 4; nt++) {
      int gn = gn0 + nt * 16 + l15;
      float b = canon[C_BO + gn];
      #pragma unroll
      for (int mt = 0; mt < 4; mt++) {
        int gm = gm0 + mt * 16 + l4 * 4;
        #pragma unroll
        for (int r = 0; r < 4; r++) {
          int gr = gm + r;
          if (gr < S_LEN) {
            float v = acc[mt][nt][r] + b;
            if (fl) ((float*)Out)[(size_t)gr * DIMC + gn] = v;
            else    ((u16*)Out)[(size_t)gr * DIMC + gn] = f2bf(v);
          }
        }
      }
    }
  }
}

// ---------------- fused RMSNorm + RoPE, wave-per-row ----------------
__global__ void norm_rope(const u16* __restrict__ Yq, const u16* __restrict__ Yk,
                          const float* __restrict__ canon, u16* __restrict__ Qh,
                          u16* __restrict__ Kh) {
  const int tid = threadIdx.x, wave = tid >> 6, lane = tid & 63;
  const int s = blockIdx.x * 4 + wave;
  const int isq = (blockIdx.y == 0);
  const u16* Y = isq ? Yq : Yk;
  const float* g = canon + (isq ? C_GQ : C_GK);
  u16* Oh = isq ? Qh : Kh;
  const float sc = isq ? (0.08838834764831845f * 1.4426950408889634f) : 1.0f;

  const u32* yrow = (const u32*)Y + (size_t)s * 768;
  float xr[12], xi[12];
  float ss = 0.f;
  #pragma unroll
  for (int i = 0; i < 12; i++) {
    u32 d = yrow[lane + 64 * i];
    float a = bf2f((u16)(d & 0xffff));
    float b = bf2f((u16)(d >> 16));
    xr[i] = a; xi[i] = b;
    ss += a * a + b * b;
  }
  #pragma unroll
  for (int dd = 1; dd < 64; dd <<= 1) ss += __shfl_xor(ss, dd, 64);
  float rms = rsqrtf(ss * (1.f / 1536.f) + 1e-6f);

  int f_ = s / FRAME, hh = (s % FRAME) / 28, ww = s % 28;
  const float* fr = canon + C_FR;
  float a = (lane < 22) ? fr[f_ * 64 + lane]
          : (lane < 43) ? fr[hh * 64 + lane]
                        : fr[ww * 64 + lane];
  float si, co;
  __sincosf(a, &si, &co);

  const float2* g2 = (const float2*)g;
  #pragma unroll
  for (int i = 0; i < 12; i++) {
    int p = lane + 64 * i;
    float2 gg = g2[p];
    float r  = xr[i] * rms * gg.x;
    float im = xi[i] * rms * gg.y;
    u32 pk = (u32)f2bf((r * co - im * si) * sc) | ((u32)f2bf((r * si + im * co) * sc) << 16);
    ((u32*)Oh)[((size_t)i * S_LEN + s) * 64 + lane] = pk;
  }
}

// ---------------- flash attention v7: 64-row Q tile, 4 waves x 16 q-rows, 4 blocks/CU --------
// v6 post-mortem: 112-row tiles shrank the grid to 432 imbalanced blocks and the
// single serial stage->compute chain exposed staging latency (occupancy stayed 19%).
// v7 keeps the v6 wave-owns-rows structure (no pair split, no cross-wave merge,
// VGPR ~52) but returns to 64-row tiles: LDS = sK 16K + sV 16K + sP 8K = 40KB ->
// 4 blocks/CU co-resident (v5 had 2). Grid back to 756 heavy-first blocks; the
// inter-block TLP (4 independent stage/compute streams per CU) hides the staging
// latency that v6 serialized.
__launch_bounds__(256, 4)
__global__ void attn_v7(const u16* __restrict__ Qh, const u16* __restrict__ Kh,
                        const u16* __restrict__ Vt, u16* __restrict__ Ab) {
  const int tid = threadIdx.x, wave = tid >> 6, lane = tid & 63;
  const int l15 = lane & 15, l4 = lane >> 4;
  const int h = blockIdx.x % 12;
  const int qb = 62 - (blockIdx.x / 12);      // heavy blocks first
  const int q0 = qb * 64;
  const int nkv = (q0 / FRAME + 1) * 7;       // full 64-wide KV tiles, frame-aligned causal
  __shared__ u16 sK[8192];       // 64 kv x 128 d (xor-swizzled rows)
  __shared__ u16 sV[8192];       // 128 d x 64 kv (xor-swizzled rows)
  __shared__ u16 sP[4][1024];    // per-wave P tile: 64 kv x 16 q

  // staging offsets: 1024 16B-chunks per tile over 256 threads (4 each for K and V)
  int koff[4], voff[4];
  #pragma unroll
  for (int i = 0; i < 4; i++) {
    int c = i * 256 + tid;
    int r = c >> 4, cc = (c & 15) ^ (r & 15);
    koff[i] = r * HD + cc * 8;
    int rv = c >> 3, cv = (c & 7) ^ (rv & 7);
    voff[i] = rv * S_PAD + cv * 8;
  }

  // Q fragments: wave owns rows q0 + wave*16 .. +15
  bf16x8 qf[4];
  {
    const u16* qp = Qh + ((size_t)h * S_LEN + q0 + wave * 16 + l15) * HD + l4 * 8;
    #pragma unroll
    for (int ks = 0; ks < 4; ks++) qf[ks] = *(const bf16x8*)(qp + ks * 32);
  }
  f32x4 o[8];
  #pragma unroll
  for (int i = 0; i < 8; i++) o[i] = (f32x4){0.f, 0.f, 0.f, 0.f};
  float l_i = 0.f;

  const u16* kb0 = Kh + (size_t)h * S_LEN * HD;
  const u16* vb0 = Vt + (size_t)h * HD * S_PAD;

  for (int t = 0; t < nkv; ++t) {
    __syncthreads();                         // previous tile fully consumed
    const u16* kb = kb0 + (size_t)t * 64 * HD;
    const u16* vb = vb0 + t * 64;
    #pragma unroll
    for (int i = 0; i < 4; i++) {
      int c = i * 256 + tid;
      gld_lds16(kb + koff[i], (char*)sK + (size_t)(c - lane) * 16);
      gld_lds16(vb + voff[i], (char*)sV + (size_t)(c - lane) * 16);
    }
    __syncthreads();                         // staging complete (vmcnt drained)

    // ---- QK^T: sT[nt][r] = S[kv = nt*16 + l4*4 + r][q = l15] ----
    f32x4 sT[4];
    #pragma unroll
    for (int nt = 0; nt < 4; nt++) sT[nt] = (f32x4){0.f, 0.f, 0.f, 0.f};
    __builtin_amdgcn_s_setprio(1);
    #pragma unroll
    for (int ks = 0; ks < 4; ks++) {
      bf16x8 kf[4];
      #pragma unroll
      for (int nt = 0; nt < 4; nt++)
        kf[nt] = *(const bf16x8*)(sK + (nt * 16 + l15) * HD + (((ks * 4 + l4) ^ l15) * 8));
      #pragma unroll
      for (int nt = 0; nt < 4; nt++)
        sT[nt] = mfma16(kf[nt], qf[ks], sT[nt]);
    }
    __builtin_amdgcn_s_setprio(0);

    // ---- softmax numerator (q pre-scaled by log2e*scale), pack to sP ----
    float rs = 0.f;
    u16* pw = sP[wave];
    #pragma unroll
    for (int nt = 0; nt < 4; nt++) {
      #pragma unroll
      for (int r = 0; r < 4; r++) {
        float p = __builtin_amdgcn_exp2f(sT[nt][r]);
        sT[nt][r] = p; rs += p;
      }
      u32 lo = (u32)f2bf(sT[nt][0]) | ((u32)f2bf(sT[nt][1]) << 16);
      u32 hi = (u32)f2bf(sT[nt][2]) | ((u32)f2bf(sT[nt][3]) << 16);
      u32 off = (u32)((nt >> 1) * 512 + ((nt & 1) * 2 + (l4 >> 1)) * 128 + l15 * 8 + (l4 & 1) * 4);
      uint2 pk; pk.x = lo; pk.y = hi;
      *(uint2*)(pw + off) = pk;
    }
    l_i += rs;

    // ---- PV: o[vt] += V^T frag x P frag ----
    #pragma unroll
    for (int ks2 = 0; ks2 < 2; ks2++) {
      bf16x8 pb = *(const bf16x8*)(sP[wave] + ks2 * 512 + lane * 8);
      __builtin_amdgcn_s_setprio(1);
      #pragma unroll
      for (int vt = 0; vt < 8; vt++) {
        bf16x8 vf = *(const bf16x8*)(sV + (vt * 16 + l15) * 64 + (((ks2 * 4 + l4) ^ (l15 & 7)) * 8));
        o[vt] = mfma16(vf, pb, o[vt]);
      }
      __builtin_amdgcn_s_setprio(0);
    }
  }

  // ---- epilogue: per-wave, no cross-wave merge ----
  l_i += __shfl_xor(l_i, 16, 64);
  l_i += __shfl_xor(l_i, 32, 64);
  float inv = 1.f / l_i;
  const size_t orow = (size_t)(q0 + wave * 16 + l15) * DIMC + (size_t)h * HD;
  #pragma unroll
  for (int vt = 0; vt < 8; vt++) {
    u32 lo = (u32)f2bf(o[vt][0] * inv) | ((u32)f2bf(o[vt][1] * inv) << 16);
    u32 hi = (u32)f2bf(o[vt][2] * inv) | ((u32)f2bf(o[vt][3] * inv) << 16);
    uint2 pk; pk.x = lo; pk.y = hi;
    *(uint2*)(Ab + orow + vt * 16 + l4 * 4) = pk;
  }
}

extern "C" void kernel_launch(void* const* d_in, const int* in_sizes, int n_in,
                              void* d_out, int out_size, void* d_ws, size_t ws_size,
                              hipStream_t stream) {
  if (ws_size < WS_NEED) return;
  char* ws = (char*)d_ws;
  int*   flag  = (int*)(ws + OFF_FLAG);
  float* canon = (float*)(ws + OFF_CANON);
  u16* xb    = (u16*)(ws + OFF_XB);
  u16* wqkvt = (u16*)(ws + OFF_WT);
  u16* wot   = (u16*)(ws + OFF_WOT);
  u16* yq    = (u16*)(ws + OFF_YQ);
  u16* yk    = (u16*)(ws + OFF_YK);
  u16* vt    = (u16*)(ws + OFF_VT);
  u16* qh    = (u16*)(ws + OFF_QH);
  u16* kh    = (u16*)(ws + OFF_KH);
  u16* ab    = (u16*)(ws + OFF_AT);

  const void* x  = d_in[0];
  const void* fr = d_in[3];
  const void* Wq = d_in[4];  const void* bq = d_in[5];
  const void* Wk = d_in[6];  const void* bk = d_in[7];
  const void* Wv = d_in[8];  const void* bv = d_in[9];
  const void* Wo = d_in[10]; const void* bo = d_in[11];
  const void* gq = d_in[12]; const void* gk = d_in[13];

  prep_all<<<12580, 256, 0, stream>>>(x, Wq, Wk, Wv, Wo, bq, bk, bv, bo, gq, gk, fr,
                                      canon, xb, wqkvt, wot, flag);
  gemm_bt<0><<<dim3(36, 32), 256, 0, stream>>>(xb, wqkvt, canon, yq, yk, vt, nullptr, flag);
  norm_rope<<<dim3(1008, 2), 256, 0, stream>>>(yq, yk, canon, qh, kh);
  attn_v7<<<756, 256, 0, stream>>>(qh, kh, vt, ab);
  gemm_bt<1><<<dim3(12, 32), 256, 0, stream>>>(ab, wot, canon, nullptr, nullptr, nullptr, d_out, flag);
}

// Round 3
// 323.878 us; speedup vs baseline: 1.1474x; 1.0489x over previous
//
#include <hip/hip_runtime.h>
#include <stdint.h>

typedef unsigned short u16;
typedef unsigned int u32;
typedef __attribute__((ext_vector_type(8))) short bf16x8;
typedef __attribute__((ext_vector_type(4))) float f32x4;

#define S_LEN 4032
#define S_PAD 4096
#define DIMC  1536
#define HD    128
#define FRAME 448

static const size_t OFF_FLAG  = 0;
static const size_t OFF_CANON = 256;
static const size_t OFF_XB    = 524288;
static const size_t OFF_WT    = OFF_XB  + 12582912;
static const size_t OFF_WOT   = OFF_WT  + 14155776;
static const size_t OFF_YQ    = OFF_WOT + 4718592;
static const size_t OFF_YK    = OFF_YQ  + 12582912;
static const size_t OFF_VT    = OFF_YK  + 12582912;
static const size_t OFF_QH    = OFF_VT  + 12582912;
static const size_t OFF_KH    = OFF_QH  + 12386304;
static const size_t OFF_AT    = OFF_KH  + 12386304;
static const size_t WS_NEED   = OFF_AT  + 12582912;

#define C_BQ 0
#define C_BO 4608
#define C_GQ 6144
#define C_GK 7680
#define C_FR 9216
#define C_TOT 74752

__device__ __forceinline__ u16 f2bf(float f) {
  union { float f; u32 u; } v; v.f = f;
  u32 u = v.u;
  u32 r = (u + 0x7fffu + ((u >> 16) & 1u)) >> 16;
  return (u16)r;
}
__device__ __forceinline__ float bf2f(u16 h) {
  union { float f; u32 u; } v; v.u = ((u32)h) << 16;
  return v.f;
}

__device__ __forceinline__ void gld_lds16(const void* g, void* l) {
  __builtin_amdgcn_global_load_lds(
      (const __attribute__((address_space(1))) void*)(uintptr_t)g,
      (__attribute__((address_space(3))) void*)(u32)(uintptr_t)l,
      16, 0, 0);
}

__device__ __forceinline__ f32x4 mfma16(bf16x8 a, bf16x8 b, f32x4 c) {
  return __builtin_amdgcn_mfma_f32_16x16x32_bf16(a, b, c, 0, 0, 0);
}

// ---------------- fused preprocessing: detect + transpose_w + convert_x + small ----------------
__global__ void prep_all(const void* __restrict__ x,
                         const void* Wq, const void* Wk, const void* Wv, const void* Wo,
                         const void* bq, const void* bk, const void* bv, const void* bo,
                         const void* gq, const void* gk, const void* fr,
                         float* __restrict__ canon, u16* __restrict__ xb,
                         u16* __restrict__ wqkvt, u16* __restrict__ wot,
                         int* __restrict__ flag) {
  __shared__ int cnt;
  __shared__ float tile[32][33];
  const int tid = threadIdx.x;
  if (tid == 0) cnt = 0;
  __syncthreads();
  int e = (((const u16*)x)[2 * tid] >> 7) & 0xff;
  if (e > 150) atomicAdd(&cnt, 1);
  __syncthreads();
  const int fl = (cnt >= 8) ? 1 : 0;   // 1 = fp32 inputs, 0 = bf16
  const int bid = blockIdx.x;
  if (bid == 0 && tid == 0) *flag = fl;

  if (bid < 9216) {
    // ---- W (K x N) -> Wt (N x K) bf16 ----
    const int z = bid / 2304;
    const int rem = bid % 2304;
    const int by = rem / 48, bx = rem % 48;
    const void* W = (z == 0) ? Wq : (z == 1) ? Wk : (z == 2) ? Wv : Wo;
    u16* dst = (z < 3) ? (wqkvt + (size_t)z * DIMC * DIMC) : wot;
    const int tx = tid & 31, ty = tid >> 5;
    const int c = bx * 32 + tx;
    #pragma unroll
    for (int i = 0; i < 4; i++) {
      int r = by * 32 + ty + i * 8;
      float v = fl ? ((const float*)W)[(size_t)r * DIMC + c]
                   : bf2f(((const u16*)W)[(size_t)r * DIMC + c]);
      tile[ty + i * 8][tx] = v;
    }
    __syncthreads();
    const int k = by * 32 + tx;
    #pragma unroll
    for (int i = 0; i < 4; i++) {
      int n = bx * 32 + ty + i * 8;
      dst[(size_t)n * DIMC + k] = f2bf(tile[tx][ty + i * 8]);
    }
  } else if (bid < 12288) {
    // ---- x -> bf16, pad rows to 4096 ----
    int i = (bid - 9216) * 256 + tid;
    if (i < (S_PAD * DIMC) / 8) {
      size_t base = (size_t)i * 8;
      int row = (int)(base / DIMC);
      union { u16 h[8]; uint4 v; } u;
      if (row < S_LEN) {
        if (fl) {
          const float* xf = (const float*)x + base;
          #pragma unroll
          for (int j = 0; j < 8; j++) u.h[j] = f2bf(xf[j]);
        } else {
          const u16* xh = (const u16*)x + base;
          #pragma unroll
          for (int j = 0; j < 8; j++) u.h[j] = xh[j];
        }
      } else {
        #pragma unroll
        for (int j = 0; j < 8; j++) u.h[j] = 0;
      }
      ((uint4*)xb)[i] = u.v;
    }
  } else {
    // ---- small tensors -> canonical fp32 ----
    for (int i = (bid - 12288) * 256 + tid; i < C_TOT; i += 292 * 256) {
      const void* src; int j;
      if      (i < 1536) { src = bq; j = i; }
      else if (i < 3072) { src = bk; j = i - 1536; }
      else if (i < 4608) { src = bv; j = i - 3072; }
      else if (i < 6144) { src = bo; j = i - 4608; }
      else if (i < 7680) { src = gq; j = i - 6144; }
      else if (i < 9216) { src = gk; j = i - 7680; }
      else               { src = fr; j = i - 9216; }
      canon[i] = fl ? ((const float*)src)[j] : bf2f(((const u16*)src)[j]);
    }
  }
}

// ---------------- GEMM: C(MxN) = A(MxK) @ Bt(NxK)^T + bias ----------------
template <int MODE>
__launch_bounds__(256, 4)
__global__ void gemm_bt(const u16* __restrict__ A, const u16* __restrict__ Bt,
                        const float* __restrict__ canon,
                        u16* __restrict__ Yq, u16* __restrict__ Yk, u16* __restrict__ Vt,
                        void* __restrict__ Out, const int* __restrict__ flagp) {
  const int bm0 = blockIdx.y * 128, bn0 = blockIdx.x * 128;
  const int tid = threadIdx.x, wave = tid >> 6, lane = tid & 63;
  const int wm = wave >> 1, wn = wave & 1;
  const int l15 = lane & 15, l4 = lane >> 4;
  __shared__ u16 sA[128 * 64];
  __shared__ u16 sB[128 * 64];
  f32x4 acc[4][4];
  #pragma unroll
  for (int i = 0; i < 4; i++)
    #pragma unroll
    for (int j = 0; j < 4; j++) acc[i][j] = (f32x4){0.f, 0.f, 0.f, 0.f};

  const int swc = ((lane & 7) ^ (lane >> 3)) * 8;
  const u16* Ab = A  + (size_t)(bm0 + (lane >> 3)) * DIMC + swc;
  const u16* Bb = Bt + (size_t)(bn0 + (lane >> 3)) * DIMC + swc;

  for (int kt = 0; kt < DIMC; kt += 64) {
    __syncthreads();
    #pragma unroll
    for (int c = 0; c < 4; c++) {
      int g = wave * 4 + c;
      gld_lds16(Ab + (size_t)g * 8 * DIMC + kt, (char*)sA + g * 1024);
      gld_lds16(Bb + (size_t)g * 8 * DIMC + kt, (char*)sB + g * 1024);
    }
    __syncthreads();
    #pragma unroll
    for (int ks = 0; ks < 2; ks++) {
      bf16x8 av[4], bvv[4];
      #pragma unroll
      for (int mt = 0; mt < 4; mt++)
        av[mt]  = *(const bf16x8*)(sA + (wm * 64 + mt * 16 + l15) * 64 +
                                   (((ks * 4 + l4) ^ (l15 & 7)) * 8));
      #pragma unroll
      for (int nt = 0; nt < 4; nt++)
        bvv[nt] = *(const bf16x8*)(sB + (wn * 64 + nt * 16 + l15) * 64 +
                                   (((ks * 4 + l4) ^ (l15 & 7)) * 8));
      #pragma unroll
      for (int mt = 0; mt < 4; mt++)
        #pragma unroll
        for (int nt = 0; nt < 4; nt++)
          acc[mt][nt] = mfma16(av[mt], bvv[nt], acc[mt][nt]);
    }
  }

  const int gm0 = bm0 + wm * 64;
  const int gn0 = bn0 + wn * 64;
  if (MODE == 0) {
    #pragma unroll
    for (int nt = 0; nt < 4; nt++) {
      int gn = gn0 + nt * 16 + l15;
      float b = canon[C_BQ + gn];
      #pragma unroll
      for (int mt = 0; mt < 4; mt++) {
        int gm = gm0 + mt * 16 + l4 * 4;
        if (gn < 1536) {
          #pragma unroll
          for (int r = 0; r < 4; r++)
            Yq[(size_t)(gm + r) * DIMC + gn] = f2bf(acc[mt][nt][r] + b);
        } else if (gn < 3072) {
          int g2 = gn - 1536;
          #pragma unroll
          for (int r = 0; r < 4; r++)
            Yk[(size_t)(gm + r) * DIMC + g2] = f2bf(acc[mt][nt][r] + b);
        } else {
          int g2 = gn - 3072;
          u32 lo = (u32)f2bf(acc[mt][nt][0] + b) | ((u32)f2bf(acc[mt][nt][1] + b) << 16);
          u32 hi = (u32)f2bf(acc[mt][nt][2] + b) | ((u32)f2bf(acc[mt][nt][3] + b) << 16);
          uint2 pk; pk.x = lo; pk.y = hi;
          *(uint2*)(Vt + (size_t)g2 * S_PAD + gm) = pk;
        }
      }
    }
  } else {
    const int fl = *flagp;
    #pragma unroll
    for (int nt = 0; nt < 4; nt++) {
      int gn = gn0 + nt * 16 + l15;
      float b = canon[C_BO + gn];
      #pragma unroll
      for (int mt = 0; mt < 4; mt++) {
        int gm = gm0 + mt * 16 + l4 * 4;
        #pragma unroll
        for (int r = 0; r < 4; r++) {
          int gr = gm + r;
          if (gr < S_LEN) {
            float v = acc[mt][nt][r] + b;
            if (fl) ((float*)Out)[(size_t)gr * DIMC + gn] = v;
            else    ((u16*)Out)[(size_t)gr * DIMC + gn] = f2bf(v);
          }
        }
      }
    }
  }
}

// ---------------- fused RMSNorm + RoPE, wave-per-row ----------------
__global__ void norm_rope(const u16* __restrict__ Yq, const u16* __restrict__ Yk,
                          const float* __restrict__ canon, u16* __restrict__ Qh,
                          u16* __restrict__ Kh) {
  const int tid = threadIdx.x, wave = tid >> 6, lane = tid & 63;
  const int s = blockIdx.x * 4 + wave;
  const int isq = (blockIdx.y == 0);
  const u16* Y = isq ? Yq : Yk;
  const float* g = canon + (isq ? C_GQ : C_GK);
  u16* Oh = isq ? Qh : Kh;
  const float sc = isq ? (0.08838834764831845f * 1.4426950408889634f) : 1.0f;

  const u32* yrow = (const u32*)Y + (size_t)s * 768;
  float xr[12], xi[12];
  float ss = 0.f;
  #pragma unroll
  for (int i = 0; i < 12; i++) {
    u32 d = yrow[lane + 64 * i];
    float a = bf2f((u16)(d & 0xffff));
    float b = bf2f((u16)(d >> 16));
    xr[i] = a; xi[i] = b;
    ss += a * a + b * b;
  }
  #pragma unroll
  for (int dd = 1; dd < 64; dd <<= 1) ss += __shfl_xor(ss, dd, 64);
  float rms = rsqrtf(ss * (1.f / 1536.f) + 1e-6f);

  int f_ = s / FRAME, hh = (s % FRAME) / 28, ww = s % 28;
  const float* fr = canon + C_FR;
  float a = (lane < 22) ? fr[f_ * 64 + lane]
          : (lane < 43) ? fr[hh * 64 + lane]
                        : fr[ww * 64 + lane];
  float si, co;
  __sincosf(a, &si, &co);

  const float2* g2 = (const float2*)g;
  #pragma unroll
  for (int i = 0; i < 12; i++) {
    int p = lane + 64 * i;
    float2 gg = g2[p];
    float r  = xr[i] * rms * gg.x;
    float im = xi[i] * rms * gg.y;
    u32 pk = (u32)f2bf((r * co - im * si) * sc) | ((u32)f2bf((r * si + im * co) * sc) << 16);
    ((u32*)Oh)[((size_t)i * S_LEN + s) * 64 + lane] = pk;
  }
}

// ---------------- flash attention v8: 64q tile, 2q-half x 2kv-half waves, dbuf staging -------
// v7 post-mortem: per-tile LDS traffic 176KB (each of 4 waves re-reads the whole K,V
// tile) -> ~67us LDS-pipe floor, plus single-buffered staging latency fully exposed.
// v8: (a) register-blocking: each wave computes 32q x 32kv, so every kf/vf LDS read
// feeds 2 MFMAs (112KB/tile, floor ~43us); (b) double-buffered K/V: stage t+1 issued
// BEFORE compute of t, one barrier per iteration -> staging latency hidden under
// compute; (c) kv-split needs a once-per-block o/l merge (amortized over >=7 tiles).
// LDS = 2x16K (K dbuf) + 2x16K (V dbuf) + 8K sP = 72KB -> 2 blocks/CU, 8 waves/CU.
// Grid 756 > 512 resident slots -> heavy-first LPT refill fixes the imbalance tail.
__launch_bounds__(256, 2)
__global__ void attn_v8(const u16* __restrict__ Qh, const u16* __restrict__ Kh,
                        const u16* __restrict__ Vt, u16* __restrict__ Ab) {
  const int tid = threadIdx.x, wave = tid >> 6, lane = tid & 63;
  const int l15 = lane & 15, l4 = lane >> 4;
  const int qh = wave >> 1;                   // q-half (0,1): rows q0+qh*32..+31
  const int kh = wave & 1;                    // kv-half (0,1): kv kh*32..+31 of each tile
  const int h = blockIdx.x % 12;
  const int qb = 62 - (blockIdx.x / 12);      // heavy blocks first (LPT)
  const int q0 = qb * 64;
  const int nkv = (q0 / FRAME + 1) * 7;       // full 64-wide KV tiles, frame-aligned causal
  __shared__ u16 sK[2][8192];                 // dbuf: 64 kv x 128 d (xor-swizzled rows)
  __shared__ u16 sV[2][8192];                 // dbuf: 128 d x 64 kv (xor-swizzled rows)
  __shared__ u16 sP[4][2][512];               // per-wave, per-qfrag: 32 kv x 16 q

  // staging offsets: 1024 16B-chunks per tile over 256 threads (4 each for K and V)
  int koff[4], voff[4];
  #pragma unroll
  for (int i = 0; i < 4; i++) {
    int c = i * 256 + tid;
    int r = c >> 4, cc = (c & 15) ^ (r & 15);
    koff[i] = r * HD + cc * 8;
    int rv = c >> 3, cv = (c & 7) ^ (rv & 7);
    voff[i] = rv * S_PAD + cv * 8;
  }

  // Q fragments: wave owns rows q0 + qh*32 .. +31 (two 16-row frags)
  bf16x8 qf[4][2];
  {
    const u16* qp = Qh + ((size_t)h * S_LEN + q0 + qh * 32 + l15) * HD + l4 * 8;
    #pragma unroll
    for (int f = 0; f < 2; f++)
      #pragma unroll
      for (int ks = 0; ks < 4; ks++)
        qf[ks][f] = *(const bf16x8*)(qp + f * 16 * HD + ks * 32);
  }
  f32x4 o[8][2];
  #pragma unroll
  for (int i = 0; i < 8; i++)
    #pragma unroll
    for (int f = 0; f < 2; f++) o[i][f] = (f32x4){0.f, 0.f, 0.f, 0.f};
  float l_i[2] = {0.f, 0.f};

  const u16* kb0 = Kh + (size_t)h * S_LEN * HD;
  const u16* vb0 = Vt + (size_t)h * HD * S_PAD;

  // prologue: stage tile 0 into buffer 0
  #pragma unroll
  for (int i = 0; i < 4; i++) {
    gld_lds16(kb0 + koff[i], (char*)sK[0] + i * 4096 + wave * 1024);
    gld_lds16(vb0 + voff[i], (char*)sV[0] + i * 4096 + wave * 1024);
  }
  __syncthreads();                            // tile 0 staged (vmcnt drained)

  for (int t = 0; t < nkv; ++t) {
    const int cur = t & 1;
    // issue next-tile stage into the other buffer (read-complete since iter t-1's barrier)
    if (t + 1 < nkv) {
      const u16* kb = kb0 + (size_t)(t + 1) * 64 * HD;
      const u16* vb = vb0 + (t + 1) * 64;
      #pragma unroll
      for (int i = 0; i < 4; i++) {
        gld_lds16(kb + koff[i], (char*)sK[cur ^ 1] + i * 4096 + wave * 1024);
        gld_lds16(vb + voff[i], (char*)sV[cur ^ 1] + i * 4096 + wave * 1024);
      }
    }

    // ---- QK^T: sT[nt][f][r] = S[kv = kh*32 + nt*16 + l4*4 + r][q = qh*32 + f*16 + l15] ----
    f32x4 sT[2][2];
    #pragma unroll
    for (int nt = 0; nt < 2; nt++)
      #pragma unroll
      for (int f = 0; f < 2; f++) sT[nt][f] = (f32x4){0.f, 0.f, 0.f, 0.f};
    __builtin_amdgcn_s_setprio(1);
    #pragma unroll
    for (int ks = 0; ks < 4; ks++) {
      bf16x8 kf[2];
      #pragma unroll
      for (int nt = 0; nt < 2; nt++)
        kf[nt] = *(const bf16x8*)(sK[cur] + (kh * 32 + nt * 16 + l15) * HD +
                                  (((ks * 4 + l4) ^ l15) * 8));
      #pragma unroll
      for (int nt = 0; nt < 2; nt++)
        #pragma unroll
        for (int f = 0; f < 2; f++)
          sT[nt][f] = mfma16(kf[nt], qf[ks][f], sT[nt][f]);
    }
    __builtin_amdgcn_s_setprio(0);

    // ---- softmax numerator (q pre-scaled by log2e*scale), pack to sP ----
    #pragma unroll
    for (int f = 0; f < 2; f++) {
      float rs = 0.f;
      u16* pw = sP[wave][f];
      #pragma unroll
      for (int nt = 0; nt < 2; nt++) {
        #pragma unroll
        for (int r = 0; r < 4; r++) {
          float p = __builtin_amdgcn_exp2f(sT[nt][f][r]);
          sT[nt][f][r] = p; rs += p;
        }
        u32 lo = (u32)f2bf(sT[nt][f][0]) | ((u32)f2bf(sT[nt][f][1]) << 16);
        u32 hi = (u32)f2bf(sT[nt][f][2]) | ((u32)f2bf(sT[nt][f][3]) << 16);
        u32 off = (u32)((nt * 2 + (l4 >> 1)) * 128 + l15 * 8 + (l4 & 1) * 4);
        uint2 pk; pk.x = lo; pk.y = hi;
        *(uint2*)(pw + off) = pk;
      }
      l_i[f] += rs;
    }

    // ---- PV (K=32, wave's kv-half): o[vt][f] += V^T frag x P frag ----
    bf16x8 pb[2];
    #pragma unroll
    for (int f = 0; f < 2; f++)
      pb[f] = *(const bf16x8*)(sP[wave][f] + lane * 8);
    __builtin_amdgcn_s_setprio(1);
    #pragma unroll
    for (int vt = 0; vt < 8; vt++) {
      bf16x8 vf = *(const bf16x8*)(sV[cur] + (vt * 16 + l15) * 64 +
                                   (((kh * 4 + l4) ^ (l15 & 7)) * 8));
      #pragma unroll
      for (int f = 0; f < 2; f++)
        o[vt][f] = mfma16(vf, pb[f], o[vt][f]);
    }
    __builtin_amdgcn_s_setprio(0);

    __syncthreads();   // all waves done reading buf[cur]; stage of t+1 complete (vmcnt 0)
  }

  // ---- epilogue: reduce l within wave, then merge kv-halves via LDS scratch ----
  #pragma unroll
  for (int f = 0; f < 2; f++) {
    l_i[f] += __shfl_xor(l_i[f], 16, 64);
    l_i[f] += __shfl_xor(l_i[f], 32, 64);
  }
  float* mb = (float*)sK;   // 32KB scratch (buffers no longer needed)
  float* lb = (float*)sP;   // small scratch
  if (kh == 1) {
    #pragma unroll
    for (int f = 0; f < 2; f++) {
      #pragma unroll
      for (int vt = 0; vt < 8; vt++)
        *(f32x4*)(mb + qh * 4096 + (f * 8 + vt) * 256 + lane * 4) = o[vt][f];
      lb[qh * 128 + f * 64 + lane] = l_i[f];
    }
  }
  __syncthreads();
  if (kh == 0) {
    #pragma unroll
    for (int f = 0; f < 2; f++) {
      float l = l_i[f] + lb[qh * 128 + f * 64 + lane];
      float inv = 1.f / l;
      const size_t orow = (size_t)(q0 + qh * 32 + f * 16 + l15) * DIMC + (size_t)h * HD;
      #pragma unroll
      for (int vt = 0; vt < 8; vt++) {
        f32x4 op = *(const f32x4*)(mb + qh * 4096 + (f * 8 + vt) * 256 + lane * 4);
        float o0 = (o[vt][f][0] + op[0]) * inv;
        float o1 = (o[vt][f][1] + op[1]) * inv;
        float o2 = (o[vt][f][2] + op[2]) * inv;
        float o3 = (o[vt][f][3] + op[3]) * inv;
        u32 lo = (u32)f2bf(o0) | ((u32)f2bf(o1) << 16);
        u32 hi = (u32)f2bf(o2) | ((u32)f2bf(o3) << 16);
        uint2 pk; pk.x = lo; pk.y = hi;
        *(uint2*)(Ab + orow + vt * 16 + l4 * 4) = pk;
      }
    }
  }
}

extern "C" void kernel_launch(void* const* d_in, const int* in_sizes, int n_in,
                              void* d_out, int out_size, void* d_ws, size_t ws_size,
                              hipStream_t stream) {
  if (ws_size < WS_NEED) return;
  char* ws = (char*)d_ws;
  int*   flag  = (int*)(ws + OFF_FLAG);
  float* canon = (float*)(ws + OFF_CANON);
  u16* xb    = (u16*)(ws + OFF_XB);
  u16* wqkvt = (u16*)(ws + OFF_WT);
  u16* wot   = (u16*)(ws + OFF_WOT);
  u16* yq    = (u16*)(ws + OFF_YQ);
  u16* yk    = (u16*)(ws + OFF_YK);
  u16* vt    = (u16*)(ws + OFF_VT);
  u16* qh    = (u16*)(ws + OFF_QH);
  u16* kh    = (u16*)(ws + OFF_KH);
  u16* ab    = (u16*)(ws + OFF_AT);

  const void* x  = d_in[0];
  const void* fr = d_in[3];
  const void* Wq = d_in[4];  const void* bq = d_in[5];
  const void* Wk = d_in[6];  const void* bk = d_in[7];
  const void* Wv = d_in[8];  const void* bv = d_in[9];
  const void* Wo = d_in[10]; const void* bo = d_in[11];
  const void* gq = d_in[12]; const void* gk = d_in[13];

  prep_all<<<12580, 256, 0, stream>>>(x, Wq, Wk, Wv, Wo, bq, bk, bv, bo, gq, gk, fr,
                                      canon, xb, wqkvt, wot, flag);
  gemm_bt<0><<<dim3(36, 32), 256, 0, stream>>>(xb, wqkvt, canon, yq, yk, vt, nullptr, flag);
  norm_rope<<<dim3(1008, 2), 256, 0, stream>>>(yq, yk, canon, qh, kh);
  attn_v8<<<756, 256, 0, stream>>>(qh, kh, vt, ab);
  gemm_bt<1><<<dim3(12, 32), 256, 0, stream>>>(ab, wot, canon, nullptr, nullptr, nullptr, d_out, flag);
}